// Round 11
// baseline (3012.724 us; speedup 1.0000x reference)
//
#include <hip/hip_runtime.h>
#include <math.h>

// SymmetricKMeans on MI355X — replicate the JAX reference trajectory.
// ROUND-10 KEY INSIGHT: jax_threefry_partitionable defaults to TRUE since
// jax 0.4.36 (Dec 2024). The reference's jax.random.randint therefore uses:
//   split (foldlike):  k2 = tf2x32(key=(0,1), counts=(0,1)) -> (s0, s1)
//   random_bits(32):   bits[i] = o0 ^ o1 of tf2x32((s0,s1), counts=(0, i))
//   randint span=1024: multiplier = 0  ->  start[i] = bits[i] % 1024
// R1-R3/R7/R8 all used the PRE-0.4.36 "original" halved-iota path -> all wrong.
// Settled: d_out = 204880 f32; ref values bf16-quantized (stub=512, thr=10.24).
// Arithmetic = XLA:CPU model (R7<->R8 showed labels are FMA-insensitive):
//   einsum dot: fmuladd chain fma(pz,cz, fma(py,cy, px*cx))
//   reduces (p2, c2, FPS dist, movement norm): plain mul/add chains
//   segment_sum: sequential scatter-add in point order
//   converge: f32 norm < 1e-3f

#define NGRP   80
#define NPTS   1024
#define NCTR   512
#define MAXIT  300
#define NBLK   320
#define NTHR   256
#define OUT_CENT  81920
#define OUT_SCORE 204800

__device__ float4   g_cent[NGRP * NCTR];   // {x,y,z,c2}
__device__ int      g_cls[NGRP * NPTS];
__device__ int      g_starts[NGRP];
__device__ unsigned g_bar[2];
__device__ unsigned g_mv[2];               // f32 bit patterns (max movement)

// ---------------- threefry2x32, exactly as JAX ----------------
__device__ __forceinline__ void tf2x32(unsigned k0, unsigned k1,
                                       unsigned x0, unsigned x1,
                                       unsigned &o0, unsigned &o1) {
  unsigned ks2 = k0 ^ k1 ^ 0x1BD11BDAu;
#define RND(r) { x0 += x1; x1 = (x1 << (r)) | (x1 >> (32 - (r))); x1 ^= x0; }
  x0 += k0; x1 += k1;
  RND(13) RND(15) RND(26) RND(6)
  x0 += k1;  x1 += ks2 + 1u;
  RND(17) RND(29) RND(16) RND(24)
  x0 += ks2; x1 += k0 + 2u;
  RND(13) RND(15) RND(26) RND(6)
  x0 += k0;  x1 += k1 + 3u;
  RND(17) RND(29) RND(16) RND(24)
  x0 += k1;  x1 += ks2 + 4u;
  RND(13) RND(15) RND(26) RND(6)
  x0 += ks2; x1 += k0 + 5u;
#undef RND
  o0 = x0; o1 = x1;
}

__global__ void init_kernel() {
  int t = threadIdx.x;
  if (t == 0) { g_bar[0] = 0u; g_bar[1] = 0u; g_mv[0] = 0u; g_mv[1] = 0u; }
  // partitionable split of key(1)=(0,1): key_j = BOTH outputs of
  // tf2x32(key, iota2x32(j)) ; j=1 -> counts (0,1) -> k2 = (s0, s1).
  unsigned s0, s1;
  tf2x32(0u, 1u, 0u, 1u, s0, s1);
  // partitionable random_bits(k2, 32, (80,)): element g uses counts (0, g),
  // output = (bits1 ^ bits2) >> (32-32). start = bits % 1024 (multiplier=0).
  if (t < NGRP) {
    unsigned o0, o1;
    tf2x32(s0, s1, 0u, (unsigned)t, o0, o1);
    g_starts[t] = (int)((o0 ^ o1) & 1023u);
  }
}

// ---------------- FPS: one block (1024 thr) per group, plain f32 ----------------
__global__ __launch_bounds__(1024) void fps_kernel(const float *__restrict__ pos) {
  const int g = blockIdx.x, t = threadIdx.x;
  const int e = g & 7;  // example = g % B (groups replica-major)
  __shared__ float sx[NPTS], sy[NPTS], sz[NPTS];
  __shared__ float wbv[16];
  __shared__ int   wbi[16];
  __shared__ int   s_last;
  const float *p = pos + (size_t)e * NPTS * 3;
  const float x = p[t * 3 + 0], y = p[t * 3 + 1], z = p[t * 3 + 2];
  sx[t] = x; sy[t] = y; sz[t] = z;
  if (t == 0) s_last = g_starts[g];
  float md = __int_as_float(0x7f800000);  // +inf
  __syncthreads();
  const int lane = t & 63, wv = t >> 6;
  for (int j = 0; j < NCTR; ++j) {
    const int last = s_last;
    const float lx = sx[last], ly = sy[last], lz = sz[last];
    if (t == 0) {  // idx[j]=last -> centroid j = p[last]; c2 plain chain
      float c2 = __fadd_rn(__fadd_rn(__fmul_rn(lx, lx), __fmul_rn(ly, ly)),
                           __fmul_rn(lz, lz));
      g_cent[(size_t)g * NCTR + j] = make_float4(lx, ly, lz, c2);
    }
    const float dx = __fsub_rn(x, lx), dy = __fsub_rn(y, ly), dz = __fsub_rn(z, lz);
    const float d = __fadd_rn(__fadd_rn(__fmul_rn(dx, dx), __fmul_rn(dy, dy)),
                              __fmul_rn(dz, dz));      // reduce emitter: plain
    md = fminf(md, d);
    // argmax(mind), first-index tie-break
    float v = md; int i = t;
    for (int off = 32; off; off >>= 1) {
      float ov = __shfl_down(v, off, 64);
      int   oi = __shfl_down(i, off, 64);
      if (ov > v || (ov == v && oi < i)) { v = ov; i = oi; }
    }
    if (lane == 0) { wbv[wv] = v; wbi[wv] = i; }
    __syncthreads();
    if (t == 0) {
      float bv = wbv[0]; int bi = wbi[0];
      for (int k = 1; k < 16; ++k)
        if (wbv[k] > bv || (wbv[k] == bv && wbi[k] < bi)) { bv = wbv[k]; bi = wbi[k]; }
      s_last = bi;
    }
    __syncthreads();
  }
}

// ---------------- software grid barrier (device scope) ----------------
__device__ __forceinline__ void gbar() {
  __threadfence();
  __syncthreads();
  if (threadIdx.x == 0) {
    unsigned gen = __hip_atomic_load(&g_bar[1], __ATOMIC_RELAXED, __HIP_MEMORY_SCOPE_AGENT);
    unsigned t = __hip_atomic_fetch_add(&g_bar[0], 1u, __ATOMIC_ACQ_REL, __HIP_MEMORY_SCOPE_AGENT);
    if (t == (unsigned)(NBLK - 1)) {
      __hip_atomic_store(&g_bar[0], 0u, __ATOMIC_RELAXED, __HIP_MEMORY_SCOPE_AGENT);
      __hip_atomic_fetch_add(&g_bar[1], 1u, __ATOMIC_ACQ_REL, __HIP_MEMORY_SCOPE_AGENT);
    } else {
      long long guard = 0;
      while (__hip_atomic_load(&g_bar[1], __ATOMIC_ACQUIRE, __HIP_MEMORY_SCOPE_AGENT) == gen) {
        __builtin_amdgcn_s_sleep(4);
        if (++guard > (1ll << 27)) break;  // safety valve
      }
    }
  }
  __syncthreads();
  __threadfence();
}

// ---------------- persistent k-means (XLA:CPU arithmetic model) ----------------
__global__ __launch_bounds__(NTHR, 2) void kmeans_kernel(
    const float *__restrict__ pos, float *__restrict__ out) {
  const int b = blockIdx.x, t = threadIdx.x;
  const int pid = b * NTHR + t;          // one point per thread
  const int g = pid >> 10;
  const int n = pid & 1023;
  const int e = g & 7;
  const float *pp = pos + ((size_t)e * NPTS + n) * 3;
  const float px = pp[0], py = pp[1], pz = pp[2];
  const float p2 = __fadd_rn(__fadd_rn(__fmul_rn(px, px), __fmul_rn(py, py)),
                             __fmul_rn(pz, pz));        // reduce: plain

  __shared__ float spx[NPTS], spy[NPTS], spz[NPTS];
  __shared__ int   slab[NPTS];
  __shared__ double red[4];

  if (b < NGRP) {  // phase-B blocks stage their group's points once
    const float *gp = pos + (size_t)(b & 7) * NPTS * 3;
    for (int k = t; k < NPTS; k += NTHR) {
      spx[k] = gp[k * 3 + 0]; spy[k] = gp[k * 3 + 1]; spz[k] = gp[k * 3 + 2];
    }
  }
  // (first gbar below provides the sync before phase B reads spx/spy/spz)

  int mycls = 0;
  for (int it = 0; it < MAXIT; ++it) {
    // ---- phase A: d2 = (p2 - 2*dot) + c2; dot = fmuladd chain (XLA dot) ----
    const float4 *cg = g_cent + (size_t)g * NCTR;
    float best = __int_as_float(0x7f800000); int bm = 0;
#pragma unroll 4
    for (int m = 0; m < NCTR; ++m) {
      float4 c = cg[m];
      float dot = fmaf(pz, c.z, fmaf(py, c.y, __fmul_rn(px, c.x)));  // FMA chain
      float d2 = __fadd_rn(__fsub_rn(p2, __fmul_rn(2.0f, dot)), c.w);
      if (d2 < best) { best = d2; bm = m; }   // strict < = first-index argmin
    }
    g_cls[pid] = bm; mycls = bm;
    gbar();

    // ---- phase B: block b<80 owns group b; 1 thread per cluster pair;
    //      strictly sequential accumulation in point order (CPU scatter) ----
    if (b < NGRP) {
      const int *gc = g_cls + (size_t)b * NPTS;
      for (int k = t; k < NPTS; k += NTHR) slab[k] = gc[k];
      __syncthreads();
      const int m1 = t, m2 = t + 256;
      float s1x = 0.f, s1y = 0.f, s1z = 0.f, s2x = 0.f, s2y = 0.f, s2z = 0.f;
      int c1 = 0, c2 = 0;
      for (int nn = 0; nn < NPTS; ++nn) {
        int lab = slab[nn];
        float xx = spx[nn], yy = spy[nn], zz = spz[nn];
        if (lab == m1) { s1x = __fadd_rn(s1x, xx); s1y = __fadd_rn(s1y, yy);
                         s1z = __fadd_rn(s1z, zz); ++c1; }
        if (lab == m2) { s2x = __fadd_rn(s2x, xx); s2y = __fadd_rn(s2y, yy);
                         s2z = __fadd_rn(s2z, zz); ++c2; }
      }
      float mx = 0.0f;
      {
        float4 oldc = g_cent[(size_t)b * NCTR + m1];
        float nx, ny, nz;
        if (c1 > 0) { float fc = (float)c1;
          nx = __fdiv_rn(s1x, fc); ny = __fdiv_rn(s1y, fc); nz = __fdiv_rn(s1z, fc); }
        else { nx = oldc.x; ny = oldc.y; nz = oldc.z; }
        float dx = __fsub_rn(oldc.x, nx), dy = __fsub_rn(oldc.y, ny), dz = __fsub_rn(oldc.z, nz);
        float nr = __fsqrt_rn(__fadd_rn(__fadd_rn(__fmul_rn(dx, dx), __fmul_rn(dy, dy)),
                                        __fmul_rn(dz, dz)));   // norm: plain
        if (nr > mx) mx = nr;
        float c2v = __fadd_rn(__fadd_rn(__fmul_rn(nx, nx), __fmul_rn(ny, ny)),
                              __fmul_rn(nz, nz));              // c2: plain
        g_cent[(size_t)b * NCTR + m1] = make_float4(nx, ny, nz, c2v);
      }
      {
        float4 oldc = g_cent[(size_t)b * NCTR + m2];
        float nx, ny, nz;
        if (c2 > 0) { float fc = (float)c2;
          nx = __fdiv_rn(s2x, fc); ny = __fdiv_rn(s2y, fc); nz = __fdiv_rn(s2z, fc); }
        else { nx = oldc.x; ny = oldc.y; nz = oldc.z; }
        float dx = __fsub_rn(oldc.x, nx), dy = __fsub_rn(oldc.y, ny), dz = __fsub_rn(oldc.z, nz);
        float nr = __fsqrt_rn(__fadd_rn(__fadd_rn(__fmul_rn(dx, dx), __fmul_rn(dy, dy)),
                                        __fmul_rn(dz, dz)));
        if (nr > mx) mx = nr;
        float c2v = __fadd_rn(__fadd_rn(__fmul_rn(nx, nx), __fmul_rn(ny, ny)),
                              __fmul_rn(nz, nz));
        g_cent[(size_t)b * NCTR + m2] = make_float4(nx, ny, nz, c2v);
      }
      // max movement: wave max then device atomic on f32 bit pattern
      for (int off = 32; off; off >>= 1) {
        float o = __shfl_down(mx, off, 64);
        if (o > mx) mx = o;
      }
      if ((t & 63) == 0) atomicMax(&g_mv[it & 1], __float_as_uint(mx));
    } else if (b == NBLK - 1 && t == 0) {
      // zero next iteration's slot during this epoch (race-free double buffer)
      __hip_atomic_store(&g_mv[(it + 1) & 1], 0u, __ATOMIC_RELAXED, __HIP_MEMORY_SCOPE_AGENT);
    }
    gbar();

    unsigned mm = __hip_atomic_load(&g_mv[it & 1], __ATOMIC_RELAXED, __HIP_MEMORY_SCOPE_AGENT);
    if (__uint_as_float(mm) < 1e-3f) break;   // all(norm < TOL), uniform
  }

  // ---- outputs (f32 buffer) ----
  out[pid] = (float)mycls;                       // classification [80*1024]
  if (pid < NGRP * NCTR) {                       // centroids [80*512*3]
    float4 c = g_cent[pid];
    float *o = out + OUT_CENT + (size_t)pid * 3;
    o[0] = c.x; o[1] = c.y; o[2] = c.z;
  }
  if (b < NGRP) {                                // scores [80]: L1, f64 accumulate
    const int   *gc = g_cls + (size_t)b * NPTS;
    const float4*cg2 = g_cent + (size_t)b * NCTR;
    double s = 0.0;
    for (int k = 0; k < 4; ++k) {
      int nn = k * NTHR + t;
      int c = gc[nn];
      float4 cc = cg2[c];
      s += (double)fabsf(__fsub_rn(spx[nn], cc.x)) +
           (double)fabsf(__fsub_rn(spy[nn], cc.y)) +
           (double)fabsf(__fsub_rn(spz[nn], cc.z));
    }
    for (int off = 32; off; off >>= 1) s += __shfl_down(s, off, 64);
    if ((t & 63) == 0) red[t >> 6] = s;
    __syncthreads();
    if (t == 0) out[OUT_SCORE + b] = (float)(red[0] + red[1] + red[2] + red[3]);
  }
}

extern "C" void kernel_launch(void *const *d_in, const int *in_sizes, int n_in,
                              void *d_out, int out_size, void *d_ws, size_t ws_size,
                              hipStream_t stream) {
  const float *pos = (const float *)d_in[0];
  float *out = (float *)d_out;   // f32 output buffer
  (void)d_ws; (void)ws_size;

  init_kernel<<<1, 128, 0, stream>>>();
  fps_kernel<<<NGRP, 1024, 0, stream>>>(pos);
  kmeans_kernel<<<NBLK, NTHR, 0, stream>>>(pos, out);
}

// Round 12
// 1823.375 us; speedup vs baseline: 1.6523x; 1.6523x over previous
//
#include <hip/hip_runtime.h>
#include <math.h>

// SymmetricKMeans on MI355X — R11 optimization round (R10 passed, absmax 0.0).
// Trajectory math is UNCHANGED (bitwise): partitionable-threefry starts, plain
// f32 chains for p2/c2/dists/norm, fmaf-chain dot, strict-< argmin, sequential
// point-order scatter adds, f32 <1e-3 convergence.
// Speedups (all order-preserving):
//  - FPS: 256thr x 4pts (4 waves) pair-rule reduction       (~1000 -> ~110 us)
//  - kmeans A: centroids staged to LDS per iter (VALU-bound)
//  - kmeans B: LDS counting-sort CSR; adds in ascending point order (bitwise
//    identical to the old 1024-scan), avg 2 members/cluster
//  - barriers: group-local 4-block barrier for A->B; ONE global barrier/iter;
//    per-group movement slots, parity double-buffered (no reset races)

#define NGRP   80
#define NPTS   1024
#define NCTR   512
#define MAXIT  300
#define NBLK   320
#define NTHR   256
#define OUT_CENT  81920
#define OUT_SCORE 204800

__device__ float4   g_cent[NGRP * NCTR];   // {x,y,z,c2}
__device__ int      g_cls[NGRP * NPTS];
__device__ unsigned g_gbar[2];             // global barrier {count, gen}
__device__ unsigned g_lbar[NGRP * 2];      // per-group 4-block barrier
__device__ float    g_move[2 * NGRP];      // parity x group movement

// ---------------- threefry2x32, exactly as JAX ----------------
__device__ __forceinline__ void tf2x32(unsigned k0, unsigned k1,
                                       unsigned x0, unsigned x1,
                                       unsigned &o0, unsigned &o1) {
  unsigned ks2 = k0 ^ k1 ^ 0x1BD11BDAu;
#define RND(r) { x0 += x1; x1 = (x1 << (r)) | (x1 >> (32 - (r))); x1 ^= x0; }
  x0 += k0; x1 += k1;
  RND(13) RND(15) RND(26) RND(6)
  x0 += k1;  x1 += ks2 + 1u;
  RND(17) RND(29) RND(16) RND(24)
  x0 += ks2; x1 += k0 + 2u;
  RND(13) RND(15) RND(26) RND(6)
  x0 += k0;  x1 += k1 + 3u;
  RND(17) RND(29) RND(16) RND(24)
  x0 += k1;  x1 += ks2 + 4u;
  RND(13) RND(15) RND(26) RND(6)
  x0 += ks2; x1 += k0 + 5u;
#undef RND
  o0 = x0; o1 = x1;
}

// ---------------- FPS: 80 blocks x 256 threads, 4 points/thread ----------------
__global__ __launch_bounds__(NTHR) void fps_kernel(const float *__restrict__ pos) {
  const int g = blockIdx.x, t = threadIdx.x;
  const int e = g & 7;
  __shared__ float sx[NPTS], sy[NPTS], sz[NPTS];
  __shared__ float wbv[4];
  __shared__ int   wbi[4];
  __shared__ int   s_last;
  if (g == 0) {  // re-init barriers for kmeans (stream-ordered; graph-safe)
    if (t < 2) g_gbar[t] = 0u;
    if (t < NGRP * 2) g_lbar[t] = 0u;
  }
  if (t == 0) {  // partitionable split + random_bits (R10-verified)
    unsigned s0, s1, o0, o1;
    tf2x32(0u, 1u, 0u, 1u, s0, s1);
    tf2x32(s0, s1, 0u, (unsigned)g, o0, o1);
    s_last = (int)((o0 ^ o1) & 1023u);
  }
  const float *p = pos + (size_t)e * NPTS * 3;
  float x[4], y[4], z[4], md[4];
#pragma unroll
  for (int k = 0; k < 4; ++k) {
    int n = t + k * NTHR;
    x[k] = p[n * 3 + 0]; y[k] = p[n * 3 + 1]; z[k] = p[n * 3 + 2];
    sx[n] = x[k]; sy[n] = y[k]; sz[n] = z[k];
    md[k] = __int_as_float(0x7f800000);
  }
  __syncthreads();
  const int lane = t & 63, wv = t >> 6;
  for (int j = 0; j < NCTR; ++j) {
    const int last = s_last;
    const float lx = sx[last], ly = sy[last], lz = sz[last];
    if (t == 0) {  // centroid j = p[last]; c2 plain chain (unchanged)
      float c2 = __fadd_rn(__fadd_rn(__fmul_rn(lx, lx), __fmul_rn(ly, ly)),
                           __fmul_rn(lz, lz));
      g_cent[(size_t)g * NCTR + j] = make_float4(lx, ly, lz, c2);
    }
    float bv = 0.0f; int bi = 0;
#pragma unroll
    for (int k = 0; k < 4; ++k) {
      const float dx = __fsub_rn(x[k], lx), dy = __fsub_rn(y[k], ly),
                  dz = __fsub_rn(z[k], lz);
      const float d = __fadd_rn(__fadd_rn(__fmul_rn(dx, dx), __fmul_rn(dy, dy)),
                                __fmul_rn(dz, dz));
      md[k] = fminf(md[k], d);
      if (k == 0) { bv = md[0]; bi = t; }
      else if (md[k] > bv) { bv = md[k]; bi = t + k * NTHR; }  // ascending idx
    }
    // pair-rule reduction -> (max, min index); order-independent
    for (int off = 32; off; off >>= 1) {
      float ov = __shfl_down(bv, off, 64);
      int   oi = __shfl_down(bi, off, 64);
      if (ov > bv || (ov == bv && oi < bi)) { bv = ov; bi = oi; }
    }
    if (lane == 0) { wbv[wv] = bv; wbi[wv] = bi; }
    __syncthreads();
    if (t == 0) {
      float fv = wbv[0]; int fi = wbi[0];
      for (int k = 1; k < 4; ++k)
        if (wbv[k] > fv || (wbv[k] == fv && wbi[k] < fi)) { fv = wbv[k]; fi = wbi[k]; }
      s_last = fi;
    }
    __syncthreads();
  }
}

// ---------------- barriers ----------------
__device__ __forceinline__ void gbar() {
  __threadfence();
  __syncthreads();
  if (threadIdx.x == 0) {
    unsigned gen = __hip_atomic_load(&g_gbar[1], __ATOMIC_RELAXED, __HIP_MEMORY_SCOPE_AGENT);
    unsigned c = __hip_atomic_fetch_add(&g_gbar[0], 1u, __ATOMIC_ACQ_REL, __HIP_MEMORY_SCOPE_AGENT);
    if (c == (unsigned)(NBLK - 1)) {
      __hip_atomic_store(&g_gbar[0], 0u, __ATOMIC_RELAXED, __HIP_MEMORY_SCOPE_AGENT);
      __hip_atomic_fetch_add(&g_gbar[1], 1u, __ATOMIC_ACQ_REL, __HIP_MEMORY_SCOPE_AGENT);
    } else {
      long long guard = 0;
      while (__hip_atomic_load(&g_gbar[1], __ATOMIC_ACQUIRE, __HIP_MEMORY_SCOPE_AGENT) == gen) {
        __builtin_amdgcn_s_sleep(2);
        if (++guard > (1ll << 25)) break;  // safety valve
      }
    }
  }
  __syncthreads();
  __threadfence();
}

__device__ __forceinline__ void lbar4(int grp) {
  __threadfence();
  __syncthreads();
  if (threadIdx.x == 0) {
    unsigned *cp = &g_lbar[grp * 2], *gp = &g_lbar[grp * 2 + 1];
    unsigned gen = __hip_atomic_load(gp, __ATOMIC_RELAXED, __HIP_MEMORY_SCOPE_AGENT);
    unsigned c = __hip_atomic_fetch_add(cp, 1u, __ATOMIC_ACQ_REL, __HIP_MEMORY_SCOPE_AGENT);
    if (c == 3u) {
      __hip_atomic_store(cp, 0u, __ATOMIC_RELAXED, __HIP_MEMORY_SCOPE_AGENT);
      __hip_atomic_fetch_add(gp, 1u, __ATOMIC_ACQ_REL, __HIP_MEMORY_SCOPE_AGENT);
    } else {
      long long guard = 0;
      while (__hip_atomic_load(gp, __ATOMIC_ACQUIRE, __HIP_MEMORY_SCOPE_AGENT) == gen) {
        __builtin_amdgcn_s_sleep(1);
        if (++guard > (1ll << 25)) break;
      }
    }
  }
  __syncthreads();
  __threadfence();
}

// ---------------- persistent k-means ----------------
__global__ __launch_bounds__(NTHR) void kmeans_kernel(
    const float *__restrict__ pos, float *__restrict__ out) {
  const int b = blockIdx.x, t = threadIdx.x;
  const int pid = b * NTHR + t;
  const int g = b >> 2;                  // group (== pid>>10)
  const int e = g & 7;
  const bool isB = (b & 3) == 0;         // block 4g does phase B for group g
  const int lane = t & 63, wv = t >> 6;
  const float *pp = pos + ((size_t)e * NPTS + (pid & 1023)) * 3;
  const float px = pp[0], py = pp[1], pz = pp[2];
  const float p2 = __fadd_rn(__fadd_rn(__fmul_rn(px, px), __fmul_rn(py, py)),
                             __fmul_rn(pz, pz));

  __shared__ float4 scent[NCTR];                       // 8KB: group centroids
  __shared__ float  spx[NPTS], spy[NPTS], spz[NPTS];   // 12KB (B only)
  __shared__ int    slab[NPTS];                        // 4KB  (B only)
  __shared__ int    cnt[NCTR], offs[NCTR];             // scan ping-pong
  __shared__ int    idx[NPTS];                         // CSR member indices
  __shared__ float  redf[4];
  __shared__ double redd[4];

  if (isB) {  // stage the group's points once
    const float *gp = pos + (size_t)e * NPTS * 3;
    for (int k = t; k < NPTS; k += NTHR) {
      spx[k] = gp[k * 3 + 0]; spy[k] = gp[k * 3 + 1]; spz[k] = gp[k * 3 + 2];
    }
  }

  int mycls = 0;
  for (int it = 0; it < MAXIT; ++it) {
    // ---- stage centroids (old c) into LDS ----
    for (int k = t; k < NCTR; k += NTHR) scent[k] = g_cent[(size_t)g * NCTR + k];
    __syncthreads();

    // ---- phase A: argmin over 512 LDS centroids (bitwise same math) ----
    float best = __int_as_float(0x7f800000); int bm = 0;
#pragma unroll 4
    for (int m = 0; m < NCTR; ++m) {
      float4 c = scent[m];
      float dot = fmaf(pz, c.z, fmaf(py, c.y, __fmul_rn(px, c.x)));
      float d2 = __fadd_rn(__fsub_rn(p2, __fmul_rn(2.0f, dot)), c.w);
      if (d2 < best) { best = d2; bm = m; }
    }
    g_cls[pid] = bm; mycls = bm;
    lbar4(g);   // group-local: all 4 blocks' labels visible

    // ---- phase B (block 4g): CSR counting-sort + sequential-order adds ----
    if (isB) {
      for (int k = 0; k < 4; ++k) {
        int n2 = t + k * NTHR;
        slab[n2] = g_cls[(size_t)g * NPTS + n2];
      }
      cnt[t] = 0; cnt[t + NTHR] = 0;
      __syncthreads();
      for (int k = 0; k < 4; ++k) atomicAdd(&cnt[slab[t + k * NTHR]], 1);
      __syncthreads();
      // Hillis-Steele inclusive scan over 512 (ping-pong cnt<->offs, 9 steps)
      int *src = cnt, *dst = offs;
      for (int d = 1; d < NCTR; d <<= 1) {
        for (int jj = t; jj < NCTR; jj += NTHR) {
          int v = src[jj];
          if (jj >= d) v += src[jj - d];
          dst[jj] = v;
        }
        __syncthreads();
        int *tmp = src; src = dst; dst = tmp;
      }
      int *incl = src, *wctr = dst;   // result in src after 9 swaps
      wctr[t] = 0; wctr[t + NTHR] = 0;
      __syncthreads();
      for (int k = 0; k < 4; ++k) {
        int n2 = t + k * NTHR;
        int c = slab[n2];
        int slot = atomicAdd(&wctr[c], 1);
        idx[(c ? incl[c - 1] : 0) + slot] = n2;
      }
      __syncthreads();
      float mx = 0.0f;
      for (int half = 0; half < 2; ++half) {
        const int c = t + half * NTHR;
        const int base = c ? incl[c - 1] : 0;
        const int kk = incl[c] - base;
        // stable order: sort this cluster's member indices ascending
        for (int i = base + 1; i < base + kk; ++i) {
          int v = idx[i], j = i - 1;
          while (j >= base && idx[j] > v) { idx[j + 1] = idx[j]; --j; }
          idx[j + 1] = v;
        }
        float4 oldc = scent[c];
        float nx, ny, nz;
        if (kk > 0) {
          float sxx = 0.f, syy = 0.f, szz = 0.f;
          for (int i = 0; i < kk; ++i) {      // same adds, same order as before
            int n2 = idx[base + i];
            sxx = __fadd_rn(sxx, spx[n2]);
            syy = __fadd_rn(syy, spy[n2]);
            szz = __fadd_rn(szz, spz[n2]);
          }
          float fc = (float)kk;
          nx = __fdiv_rn(sxx, fc); ny = __fdiv_rn(syy, fc); nz = __fdiv_rn(szz, fc);
        } else { nx = oldc.x; ny = oldc.y; nz = oldc.z; }
        float dx = __fsub_rn(oldc.x, nx), dy = __fsub_rn(oldc.y, ny),
              dz = __fsub_rn(oldc.z, nz);
        float nr = __fsqrt_rn(__fadd_rn(__fadd_rn(__fmul_rn(dx, dx), __fmul_rn(dy, dy)),
                                        __fmul_rn(dz, dz)));
        if (nr > mx) mx = nr;
        float c2v = __fadd_rn(__fadd_rn(__fmul_rn(nx, nx), __fmul_rn(ny, ny)),
                              __fmul_rn(nz, nz));
        g_cent[(size_t)g * NCTR + c] = make_float4(nx, ny, nz, c2v);
      }
      for (int off = 32; off; off >>= 1) {
        float o = __shfl_down(mx, off, 64);
        if (o > mx) mx = o;
      }
      if (lane == 0) redf[wv] = mx;
      __syncthreads();
      if (t == 0)
        g_move[(it & 1) * NGRP + g] =
            fmaxf(fmaxf(redf[0], redf[1]), fmaxf(redf[2], redf[3]));
    }
    gbar();   // single global barrier per iteration

    // ---- uniform convergence decision from 80 per-group slots ----
    float v = (t < NGRP) ? g_move[(it & 1) * NGRP + t] : 0.0f;
    for (int off = 32; off; off >>= 1) {
      float o = __shfl_down(v, off, 64);
      if (o > v) v = o;
    }
    if (lane == 0) redf[wv] = v;
    __syncthreads();
    float mm = fmaxf(fmaxf(redf[0], redf[1]), fmaxf(redf[2], redf[3]));
    if (mm < 1e-3f) break;   // f32 compare, same as R10
  }

  // ---- outputs (f32 buffer) ----
  out[pid] = (float)mycls;                       // classification
  if (pid < NGRP * NCTR) {                       // centroids
    float4 c = g_cent[pid];
    float *o = out + OUT_CENT + (size_t)pid * 3;
    o[0] = c.x; o[1] = c.y; o[2] = c.z;
  }
  if (isB) {                                     // score of group g (f64 accum)
    const float4 *cg2 = g_cent + (size_t)g * NCTR;
    double s = 0.0;
    for (int k = 0; k < 4; ++k) {
      int nn = k * NTHR + t;
      int c = slab[nn];                          // final labels (from last B)
      float4 cc = cg2[c];
      s += (double)fabsf(__fsub_rn(spx[nn], cc.x)) +
           (double)fabsf(__fsub_rn(spy[nn], cc.y)) +
           (double)fabsf(__fsub_rn(spz[nn], cc.z));
    }
    for (int off = 32; off; off >>= 1) s += __shfl_down(s, off, 64);
    if (lane == 0) redd[wv] = s;
    __syncthreads();
    if (t == 0) out[OUT_SCORE + g] = (float)(redd[0] + redd[1] + redd[2] + redd[3]);
  }
}

extern "C" void kernel_launch(void *const *d_in, const int *in_sizes, int n_in,
                              void *d_out, int out_size, void *d_ws, size_t ws_size,
                              hipStream_t stream) {
  const float *pos = (const float *)d_in[0];
  float *out = (float *)d_out;
  (void)d_ws; (void)ws_size;

  fps_kernel<<<NGRP, NTHR, 0, stream>>>(pos);
  kmeans_kernel<<<NBLK, NTHR, 0, stream>>>(pos, out);
}

// Round 13
// 1223.609 us; speedup vs baseline: 2.4622x; 1.4902x over previous
//
#include <hip/hip_runtime.h>
#include <math.h>

// SymmetricKMeans on MI355X — R12: kill the barrier serialization.
// R11 forensics: T ~= 15 iterations, ~90 us/iter of stall — the 320-arrival
// single-line global barrier (~300cyc/RMW serialized cross-XCD) + per-iter
// centroid global round-trips. Fixes (arithmetic untouched, bitwise R10/R11):
//  - FPS: ONE wave per group (64thr x 16pts), no syncthreads in the 512-loop
//  - kmeans: centroids persistent in LDS; phase B REPLICATED in all 4 blocks
//    of a group (identical f32 ops => identical copies) — no centroid traffic
//  - global coupling = 1-bit convergence: tree barrier 80 reps -> 8 supers ->
//    root publishes packed {gen,decision}; per-group lbar4 on private lines
//  - phase A: stripe-4 argmin (4 independent chains, order-preserving combine)

#define NGRP   80
#define NPTS   1024
#define NCTR   512
#define MAXIT  300
#define NBLK   320
#define NTHR   256
#define NSUP   8
#define OUT_CENT  81920
#define OUT_SCORE 204800

__device__ float4   g_cent[NGRP * NCTR];   // FPS output -> kmeans init
__device__ int      g_cls[NGRP * NPTS];
__device__ unsigned g_lbar[NGRP * 32];     // per-group line: [0]=cnt,[1]=gen
__device__ unsigned g_sup[NSUP * 32];      // packed: cnt<<16 | conv_sum
__device__ unsigned g_root[32];            // packed: cnt<<16 | conv_sum
__device__ unsigned g_pub[32];             // ((it+1)&0xFFFF) | allconv<<31

// ---------------- threefry2x32, exactly as JAX (partitionable path) ----------------
__device__ __forceinline__ void tf2x32(unsigned k0, unsigned k1,
                                       unsigned x0, unsigned x1,
                                       unsigned &o0, unsigned &o1) {
  unsigned ks2 = k0 ^ k1 ^ 0x1BD11BDAu;
#define RND(r) { x0 += x1; x1 = (x1 << (r)) | (x1 >> (32 - (r))); x1 ^= x0; }
  x0 += k0; x1 += k1;
  RND(13) RND(15) RND(26) RND(6)
  x0 += k1;  x1 += ks2 + 1u;
  RND(17) RND(29) RND(16) RND(24)
  x0 += ks2; x1 += k0 + 2u;
  RND(13) RND(15) RND(26) RND(6)
  x0 += k0;  x1 += k1 + 3u;
  RND(17) RND(29) RND(16) RND(24)
  x0 += k1;  x1 += ks2 + 4u;
  RND(13) RND(15) RND(26) RND(6)
  x0 += ks2; x1 += k0 + 5u;
#undef RND
  o0 = x0; o1 = x1;
}

// ---------------- FPS: one WAVE per group, 16 points/lane ----------------
__global__ __launch_bounds__(64) void fps_kernel(const float *__restrict__ pos) {
  const int g = blockIdx.x, t = threadIdx.x;
  const int e = g & 7;
  __shared__ float sx[NPTS], sy[NPTS], sz[NPTS];
  if (g == 0) {  // re-init kmeans sync state every launch (graph-safe)
    for (int k = t; k < NGRP * 32; k += 64) g_lbar[k] = 0u;
    for (int k = t; k < NSUP * 32; k += 64) g_sup[k] = 0u;
    if (t == 0) { g_root[0] = 0u; g_pub[0] = 0u; }
  }
  unsigned s0, s1, o0, o1;            // partitionable split + random_bits
  tf2x32(0u, 1u, 0u, 1u, s0, s1);
  tf2x32(s0, s1, 0u, (unsigned)g, o0, o1);
  int last = (int)((o0 ^ o1) & 1023u);

  const float *p = pos + (size_t)e * NPTS * 3;
  float x[16], y[16], z[16], md[16];
#pragma unroll
  for (int k = 0; k < 16; ++k) {
    int n = k * 64 + t;
    x[k] = p[n * 3 + 0]; y[k] = p[n * 3 + 1]; z[k] = p[n * 3 + 2];
    sx[n] = x[k]; sy[n] = y[k]; sz[n] = z[k];
    md[k] = __int_as_float(0x7f800000);
  }
  __syncthreads();  // cross-lane LDS visibility (single wave; loop has no LDS writes)
  for (int j = 0; j < NCTR; ++j) {
    const float lx = sx[last], ly = sy[last], lz = sz[last];
    if (t == 0) {   // centroid j = p[last]; c2 plain chain (unchanged)
      float c2 = __fadd_rn(__fadd_rn(__fmul_rn(lx, lx), __fmul_rn(ly, ly)),
                           __fmul_rn(lz, lz));
      g_cent[(size_t)g * NCTR + j] = make_float4(lx, ly, lz, c2);
    }
    float bv = 0.0f; int bi = 0;
#pragma unroll
    for (int k = 0; k < 16; ++k) {
      const float dx = __fsub_rn(x[k], lx), dy = __fsub_rn(y[k], ly),
                  dz = __fsub_rn(z[k], lz);
      const float d = __fadd_rn(__fadd_rn(__fmul_rn(dx, dx), __fmul_rn(dy, dy)),
                                __fmul_rn(dz, dz));
      md[k] = fminf(md[k], d);
      if (k == 0) { bv = md[0]; bi = t; }
      else if (md[k] > bv) { bv = md[k]; bi = k * 64 + t; }  // keeps first idx
    }
    for (int off = 32; off; off >>= 1) {   // pair rule: (max, min index)
      float ov = __shfl_down(bv, off, 64);
      int   oi = __shfl_down(bi, off, 64);
      if (ov > bv || (ov == bv && oi < bi)) { bv = ov; bi = oi; }
    }
    last = __shfl(bi, 0, 64);
  }
}

// ---------------- per-group 4-block barrier (private cacheline) ----------------
__device__ __forceinline__ void lbar4(int grp) {
  __threadfence();
  __syncthreads();
  if (threadIdx.x == 0) {
    unsigned *cp = &g_lbar[grp * 32], *gp = &g_lbar[grp * 32 + 1];
    unsigned gen = __hip_atomic_load(gp, __ATOMIC_RELAXED, __HIP_MEMORY_SCOPE_AGENT);
    unsigned c = __hip_atomic_fetch_add(cp, 1u, __ATOMIC_ACQ_REL, __HIP_MEMORY_SCOPE_AGENT);
    if (c == 3u) {
      __hip_atomic_store(cp, 0u, __ATOMIC_RELAXED, __HIP_MEMORY_SCOPE_AGENT);
      __hip_atomic_fetch_add(gp, 1u, __ATOMIC_ACQ_REL, __HIP_MEMORY_SCOPE_AGENT);
    } else {
      long long guard = 0;
      while (__hip_atomic_load(gp, __ATOMIC_ACQUIRE, __HIP_MEMORY_SCOPE_AGENT) == gen) {
        __builtin_amdgcn_s_sleep(1);
        if (++guard > (1ll << 24)) break;  // safety valve
      }
    }
  }
  __syncthreads();
  __threadfence();
}

// ---------------- persistent k-means ----------------
__global__ __launch_bounds__(NTHR) void kmeans_kernel(
    const float *__restrict__ pos, float *__restrict__ out) {
  const int b = blockIdx.x, t = threadIdx.x;
  const int pid = b * NTHR + t;
  const int g = b >> 2;                  // group
  const int e = g & 7;
  const int n_own = pid & 1023;          // point index within group
  const bool isRep = (b & 3) == 0;
  const int lane = t & 63, wv = t >> 6;
  const float *pp = pos + ((size_t)e * NPTS + n_own) * 3;
  const float px = pp[0], py = pp[1], pz = pp[2];
  const float p2 = __fadd_rn(__fadd_rn(__fmul_rn(px, px), __fmul_rn(py, py)),
                             __fmul_rn(pz, pz));

  __shared__ float4 scent[NCTR];                        // persistent centroids
  __shared__ float  spx[NPTS], spy[NPTS], spz[NPTS];
  __shared__ int    slab[NPTS];
  __shared__ int    cnt[NCTR], offs[NCTR];
  __shared__ int    idx[NPTS];
  __shared__ float  redf[4];
  __shared__ double redd[4];
  __shared__ unsigned s_pub;

  {  // stage points + initial centroids (once)
    const float *gp = pos + (size_t)e * NPTS * 3;
    for (int k = t; k < NPTS; k += NTHR) {
      spx[k] = gp[k * 3 + 0]; spy[k] = gp[k * 3 + 1]; spz[k] = gp[k * 3 + 2];
    }
    for (int k = t; k < NCTR; k += NTHR) scent[k] = g_cent[(size_t)g * NCTR + k];
  }
  __syncthreads();

  int mycls = 0;
  for (int it = 0; it < MAXIT; ++it) {
    // ---- phase A: stripe-4 argmin (bitwise same result as sequential) ----
    float best0 = __int_as_float(0x7f800000), best1 = best0,
          best2 = best0, best3 = best0;
    int im0 = 0, im1 = 0, im2 = 0, im3 = 0;
#pragma unroll 2
    for (int m = 0; m < NCTR / 4; ++m) {
      float4 c0 = scent[m], c1 = scent[m + 128], c2v = scent[m + 256],
             c3 = scent[m + 384];
      float d0 = __fadd_rn(__fsub_rn(p2, __fmul_rn(2.0f,
                    fmaf(pz, c0.z, fmaf(py, c0.y, __fmul_rn(px, c0.x))))), c0.w);
      float d1 = __fadd_rn(__fsub_rn(p2, __fmul_rn(2.0f,
                    fmaf(pz, c1.z, fmaf(py, c1.y, __fmul_rn(px, c1.x))))), c1.w);
      float d2 = __fadd_rn(__fsub_rn(p2, __fmul_rn(2.0f,
                    fmaf(pz, c2v.z, fmaf(py, c2v.y, __fmul_rn(px, c2v.x))))), c2v.w);
      float d3 = __fadd_rn(__fsub_rn(p2, __fmul_rn(2.0f,
                    fmaf(pz, c3.z, fmaf(py, c3.y, __fmul_rn(px, c3.x))))), c3.w);
      if (d0 < best0) { best0 = d0; im0 = m; }
      if (d1 < best1) { best1 = d1; im1 = m; }
      if (d2 < best2) { best2 = d2; im2 = m; }
      if (d3 < best3) { best3 = d3; im3 = m; }
    }
    float best = best0; int bm = im0;                 // stripe priority = m order
    if (best1 < best) { best = best1; bm = 128 + im1; }
    if (best2 < best) { best = best2; bm = 256 + im2; }
    if (best3 < best) { best = best3; bm = 384 + im3; }
    g_cls[(size_t)g * NPTS + n_own] = bm; mycls = bm;
    lbar4(g);

    // ---- phase B (REPLICATED in all 4 blocks; identical ops everywhere) ----
    for (int k = t; k < NPTS; k += NTHR) slab[k] = g_cls[(size_t)g * NPTS + k];
    cnt[t] = 0; cnt[t + NTHR] = 0;
    __syncthreads();
    for (int k = 0; k < 4; ++k) atomicAdd(&cnt[slab[t + k * NTHR]], 1);
    __syncthreads();
    int *src = cnt, *dst = offs;            // Hillis-Steele scan over 512
    for (int d = 1; d < NCTR; d <<= 1) {
      for (int jj = t; jj < NCTR; jj += NTHR) {
        int v = src[jj];
        if (jj >= d) v += src[jj - d];
        dst[jj] = v;
      }
      __syncthreads();
      int *tmp = src; src = dst; dst = tmp;
    }
    int *incl = src, *wctr = dst;
    wctr[t] = 0; wctr[t + NTHR] = 0;
    __syncthreads();
    for (int k = 0; k < 4; ++k) {
      int n2 = t + k * NTHR;
      int c = slab[n2];
      int slot = atomicAdd(&wctr[c], 1);
      idx[(c ? incl[c - 1] : 0) + slot] = n2;
    }
    __syncthreads();
    float mx = 0.0f;
    for (int half = 0; half < 2; ++half) {
      const int c = t + half * NTHR;
      const int base = c ? incl[c - 1] : 0;
      const int kk = incl[c] - base;
      for (int i = base + 1; i < base + kk; ++i) {   // ascending point order
        int v = idx[i], j = i - 1;
        while (j >= base && idx[j] > v) { idx[j + 1] = idx[j]; --j; }
        idx[j + 1] = v;
      }
      float4 oldc = scent[c];
      float nx, ny, nz;
      if (kk > 0) {
        float sxx = 0.f, syy = 0.f, szz = 0.f;
        for (int i = 0; i < kk; ++i) {               // same adds, same order
          int n2 = idx[base + i];
          sxx = __fadd_rn(sxx, spx[n2]);
          syy = __fadd_rn(syy, spy[n2]);
          szz = __fadd_rn(szz, spz[n2]);
        }
        float fc = (float)kk;
        nx = __fdiv_rn(sxx, fc); ny = __fdiv_rn(syy, fc); nz = __fdiv_rn(szz, fc);
      } else { nx = oldc.x; ny = oldc.y; nz = oldc.z; }
      float dx = __fsub_rn(oldc.x, nx), dy = __fsub_rn(oldc.y, ny),
            dz = __fsub_rn(oldc.z, nz);
      float nr = __fsqrt_rn(__fadd_rn(__fadd_rn(__fmul_rn(dx, dx), __fmul_rn(dy, dy)),
                                      __fmul_rn(dz, dz)));
      if (nr > mx) mx = nr;
      float c2v2 = __fadd_rn(__fadd_rn(__fmul_rn(nx, nx), __fmul_rn(ny, ny)),
                             __fmul_rn(nz, nz));
      scent[c] = make_float4(nx, ny, nz, c2v2);      // LDS-persistent update
    }
    for (int off = 32; off; off >>= 1) {
      float o = __shfl_down(mx, off, 64);
      if (o > mx) mx = o;
    }
    if (lane == 0) redf[wv] = mx;
    __syncthreads();

    // ---- global convergence decision: 80 -> 8 -> 1 tree, packed publish ----
    if (t == 0) {
      if (isRep) {
        float bmx = fmaxf(fmaxf(redf[0], redf[1]), fmaxf(redf[2], redf[3]));
        unsigned conv = (bmx < 1e-3f) ? 1u : 0u;     // f32 compare (unchanged)
        int s = g / 10;
        unsigned old = __hip_atomic_fetch_add(&g_sup[s * 32], 0x10000u + conv,
                         __ATOMIC_ACQ_REL, __HIP_MEMORY_SCOPE_AGENT);
        if ((old >> 16) == 9u) {                     // last of 10 groups
          unsigned sconv = (((old & 0xFFFFu) + conv) == 10u) ? 1u : 0u;
          __hip_atomic_store(&g_sup[s * 32], 0u, __ATOMIC_RELAXED, __HIP_MEMORY_SCOPE_AGENT);
          unsigned old2 = __hip_atomic_fetch_add(&g_root[0], 0x10000u + sconv,
                            __ATOMIC_ACQ_REL, __HIP_MEMORY_SCOPE_AGENT);
          if ((old2 >> 16) == (unsigned)(NSUP - 1)) {  // last of 8 supers
            unsigned allc = (((old2 & 0xFFFFu) + sconv) == (unsigned)NSUP) ? 1u : 0u;
            __hip_atomic_store(&g_root[0], 0u, __ATOMIC_RELAXED, __HIP_MEMORY_SCOPE_AGENT);
            __hip_atomic_store(&g_pub[0],
                (unsigned)((it + 1) & 0xFFFF) | (allc << 31),
                __ATOMIC_RELEASE, __HIP_MEMORY_SCOPE_AGENT);
          }
        }
      }
      unsigned want = (unsigned)((it + 1) & 0xFFFF);
      unsigned pub; long long guard = 0;
      do {
        pub = __hip_atomic_load(&g_pub[0], __ATOMIC_ACQUIRE, __HIP_MEMORY_SCOPE_AGENT);
        if ((pub & 0xFFFFu) == want) break;
        __builtin_amdgcn_s_sleep(1);
      } while (++guard < (1ll << 24));               // safety valve
      s_pub = pub;
    }
    __syncthreads();
    if (s_pub >> 31) break;                          // uniform across grid
  }

  // ---- outputs (f32 buffer) ----
  out[pid] = (float)mycls;                           // classification
  if (isRep) {
    for (int half = 0; half < 2; ++half) {           // centroids from LDS
      int c = t + half * NTHR;
      float4 cc = scent[c];
      float *o = out + OUT_CENT + ((size_t)g * NCTR + c) * 3;
      o[0] = cc.x; o[1] = cc.y; o[2] = cc.z;
    }
    double s = 0.0;                                  // score: L1, f64 accumulate
    for (int k = 0; k < 4; ++k) {
      int nn = k * NTHR + t;
      float4 cc = scent[slab[nn]];
      s += (double)fabsf(__fsub_rn(spx[nn], cc.x)) +
           (double)fabsf(__fsub_rn(spy[nn], cc.y)) +
           (double)fabsf(__fsub_rn(spz[nn], cc.z));
    }
    for (int off = 32; off; off >>= 1) s += __shfl_down(s, off, 64);
    if (lane == 0) redd[wv] = s;
    __syncthreads();
    if (t == 0) out[OUT_SCORE + g] = (float)(redd[0] + redd[1] + redd[2] + redd[3]);
  }
}

extern "C" void kernel_launch(void *const *d_in, const int *in_sizes, int n_in,
                              void *d_out, int out_size, void *d_ws, size_t ws_size,
                              hipStream_t stream) {
  const float *pos = (const float *)d_in[0];
  float *out = (float *)d_out;
  (void)d_ws; (void)ws_size;

  fps_kernel<<<NGRP, 64, 0, stream>>>(pos);
  kmeans_kernel<<<NBLK, NTHR, 0, stream>>>(pos, out);
}